// Round 6
// baseline (57.879 us; speedup 1.0000x reference)
//
#include <hip/hip_runtime.h>

#define BB 8
#define NN 2048
#define FF 64
#define LOG2E 1.4426950408889634f
#define ROWS_PER_BLOCK 32

typedef float f32x4 __attribute__((ext_vector_type(4)));

__device__ __forceinline__ float waveMax(float v) {
    #pragma unroll
    for (int o = 32; o > 0; o >>= 1) v = fmaxf(v, __shfl_xor(v, o, 64));
    return v;
}
__device__ __forceinline__ float waveSum(float v) {
    #pragma unroll
    for (int o = 32; o > 0; o >>= 1) v += __shfl_xor(v, o, 64);
    return v;
}
__device__ __forceinline__ float lk(float x) { return fmaxf(x, 0.2f * x); }

// One kernel does everything. Block = 32 output rows of one batch.
// Redundant per-block work (fold + batch T row) is all L2-resident reads and
// trivial FLOPs; removes two dependent launches from the graph.
__global__ __launch_bounds__(256) void gat_fused(const float* __restrict__ enc,
                                                 const float* __restrict__ kmat,
                                                 const float* __restrict__ aks,
                                                 const float* __restrict__ akn,
                                                 float* __restrict__ out) {
    __shared__ float ws[FF], wn[FF];
    __shared__ float Tld[NN];          // this batch's T row (prescaled by log2e)
    __shared__ float sS[ROWS_PER_BLOCK];
    __shared__ float wred[4];

    const int tid  = threadIdx.x;
    const int wave = tid >> 6, lane = tid & 63;
    const int row0 = blockIdx.x * ROWS_PER_BLOCK;  // global row base
    const int b    = row0 >> 11;                   // batch (N = 2048)

    // ---- Phase 1: fold attention vectors through projection ----
    if (tid < FF) {
        float s = 0.f, t = 0.f;
        #pragma unroll
        for (int o = 0; o < FF; ++o) {
            float k = kmat[tid * FF + o];
            s += k * aks[o];
            t += k * akn[o];
        }
        ws[tid] = s;
        wn[tid] = t;
    }
    __syncthreads();

    // ---- Phase 2: batch T row (2048 dots) + own-row S scores ----
    const float* encb = enc + (size_t)b * NN * FF;
    const f32x4* v4 = (const f32x4*)wn;
    const f32x4* w4 = (const f32x4*)ws;
    #pragma unroll
    for (int m = tid; m < NN; m += 256) {
        const f32x4* e4 = (const f32x4*)(encb + (size_t)m * FF);
        float t = 0.f;
        #pragma unroll
        for (int j = 0; j < FF / 4; ++j) {
            f32x4 e = e4[j], v = v4[j];
            t += e.x * v.x + e.y * v.y + e.z * v.z + e.w * v.w;
        }
        Tld[m] = t * LOG2E;
    }
    if (tid < ROWS_PER_BLOCK) {
        const f32x4* e4 = (const f32x4*)(enc + (size_t)(row0 + tid) * FF);
        float s = 0.f;
        #pragma unroll
        for (int j = 0; j < FF / 4; ++j) {
            f32x4 e = e4[j], w = w4[j];
            s += e.x * w.x + e.y * w.y + e.z * w.z + e.w * w.w;
        }
        sS[tid] = s * LOG2E;
    }
    __syncthreads();

    // ---- Phase 3: each wave mirrors the full T row into regs; block max ----
    const f32x4* t4 = (const f32x4*)Tld;
    f32x4 t[8];
    float tm = -3.4e38f;
    #pragma unroll
    for (int j = 0; j < 8; ++j) {
        t[j] = t4[lane + 64 * j];
        tm = fmaxf(tm, fmaxf(fmaxf(t[j].x, t[j].y), fmaxf(t[j].z, t[j].w)));
    }
    tm = waveMax(tm);
    if (lane == 0) wred[wave] = tm;
    __syncthreads();
    const float tmax = fmaxf(fmaxf(wred[0], wred[1]), fmaxf(wred[2], wred[3]));

    // Per-element branch factors: E = 2^(t-tmax), F = 2^(0.2(t-tmax)).
    f32x4 E[8], F[8];
    #pragma unroll
    for (int j = 0; j < 8; ++j) {
        f32x4 d;
        d.x = t[j].x - tmax; d.y = t[j].y - tmax;
        d.z = t[j].z - tmax; d.w = t[j].w - tmax;
        E[j].x = __builtin_exp2f(d.x); E[j].y = __builtin_exp2f(d.y);
        E[j].z = __builtin_exp2f(d.z); E[j].w = __builtin_exp2f(d.w);
        F[j].x = __builtin_exp2f(0.2f * d.x); F[j].y = __builtin_exp2f(0.2f * d.y);
        F[j].z = __builtin_exp2f(0.2f * d.z); F[j].w = __builtin_exp2f(0.2f * d.w);
    }

    // ---- Phase 4: wave w handles rows w, w+4, ..., w+28 ----
    #pragma unroll
    for (int k = 0; k < 8; ++k) {
        const int r = wave + 4 * k;
        const float s = sS[r];                 // LDS broadcast
        const float u = s + tmax;
        const float M = lk(u);                 // exact rowmax (leaky monotone)
        const float A  = __builtin_exp2f(u - M);
        const float Bc = __builtin_exp2f(0.2f * u - M);

        // e = max(A*E, Bc*F) == 2^(leaky(s+t)-M) exactly (pos wins iff s+t>0)
        f32x4 e[8];
        float ls = 0.f;
        #pragma unroll
        for (int j = 0; j < 8; ++j) {
            e[j].x = fmaxf(A * E[j].x, Bc * F[j].x);
            e[j].y = fmaxf(A * E[j].y, Bc * F[j].y);
            e[j].z = fmaxf(A * E[j].z, Bc * F[j].z);
            e[j].w = fmaxf(A * E[j].w, Bc * F[j].w);
            ls += (e[j].x + e[j].y) + (e[j].z + e[j].w);
        }
        ls = waveSum(ls);
        const float inv = 1.f / ls;

        f32x4* o4 = (f32x4*)(out + (size_t)(row0 + r) * NN);
        #pragma unroll
        for (int j = 0; j < 8; ++j) {
            f32x4 o;
            o.x = e[j].x * inv; o.y = e[j].y * inv;
            o.z = e[j].z * inv; o.w = e[j].w * inv;
            __builtin_nontemporal_store(o, &o4[lane + 64 * j]);
        }
    }
}

extern "C" void kernel_launch(void* const* d_in, const int* in_sizes, int n_in,
                              void* d_out, int out_size, void* d_ws, size_t ws_size,
                              hipStream_t stream) {
    const float* enc  = (const float*)d_in[0];  // [B,N,F]
    const float* kmat = (const float*)d_in[1];  // [F,1,F]
    const float* aks  = (const float*)d_in[2];  // [F,1,1]
    const float* akn  = (const float*)d_in[3];  // [F,1,1]
    float* out = (float*)d_out;                 // [B,N,N]

    gat_fused<<<BB * NN / ROWS_PER_BLOCK, 256, 0, stream>>>(enc, kmat, aks, akn, out);
}

// Round 7
// 33.661 us; speedup vs baseline: 1.7195x; 1.7195x over previous
//
#include <hip/hip_runtime.h>

#define BB 8
#define NN 2048
#define FF 64
#define LOG2E 1.4426950408889634f
#define ROWS_PER_WAVE 4

typedef float f32x4 __attribute__((ext_vector_type(4)));

// ---------------- Kernel A: fused fold + per-node scores (prescaled) ---------
__global__ __launch_bounds__(256) void scores_fused(const float* __restrict__ enc,
                                                    const float* __restrict__ kmat,
                                                    const float* __restrict__ aks,
                                                    const float* __restrict__ akn,
                                                    float* __restrict__ S,
                                                    float* __restrict__ T) {
    __shared__ float ws[FF], wn[FF];
    const int tid = threadIdx.x;
    if (tid < FF) {
        float s = 0.f, t = 0.f;
        #pragma unroll
        for (int o = 0; o < FF; ++o) {
            float k = kmat[tid * FF + o];
            s += k * aks[o];
            t += k * akn[o];
        }
        ws[tid] = s;
        wn[tid] = t;
    }
    __syncthreads();

    const int g = blockIdx.x * 256 + tid;
    const f32x4* e4 = (const f32x4*)(enc + (size_t)g * FF);
    const f32x4* w4 = (const f32x4*)ws;
    const f32x4* v4 = (const f32x4*)wn;
    float s = 0.f, t = 0.f;
    #pragma unroll
    for (int j = 0; j < FF / 4; ++j) {
        f32x4 e = e4[j];
        f32x4 w = w4[j];
        f32x4 v = v4[j];
        s += e.x * w.x + e.y * w.y + e.z * w.z + e.w * w.w;
        t += e.x * v.x + e.y * v.y + e.z * v.z + e.w * v.w;
    }
    S[g] = s * LOG2E;
    T[g] = t * LOG2E;
}

// ---------------- Kernel B: factored softmax, REGULAR stores (A/B vs NT) -----
__device__ __forceinline__ float waveMax(float v) {
    #pragma unroll
    for (int o = 32; o > 0; o >>= 1) v = fmaxf(v, __shfl_xor(v, o, 64));
    return v;
}
__device__ __forceinline__ float waveSum(float v) {
    #pragma unroll
    for (int o = 32; o > 0; o >>= 1) v += __shfl_xor(v, o, 64);
    return v;
}
__device__ __forceinline__ float lk(float x) { return fmaxf(x, 0.2f * x); }

__global__ __launch_bounds__(256) void softmax_kernel(const float* __restrict__ S,
                                                      const float* __restrict__ T,
                                                      float* __restrict__ out) {
    const int wave = threadIdx.x >> 6;
    const int lane = threadIdx.x & 63;
    const int row0 = (blockIdx.x * 4 + wave) * ROWS_PER_WAVE;  // same batch
    const int b    = row0 >> 11;                               // N = 2048

    const f32x4* t4 = (const f32x4*)(T + (size_t)b * NN);

    // Load shared T row once; reduce its max.
    f32x4 t[8];
    float tm = -3.4e38f;
    #pragma unroll
    for (int j = 0; j < 8; ++j) {
        t[j] = t4[lane + 64 * j];
        tm = fmaxf(tm, fmaxf(fmaxf(t[j].x, t[j].y), fmaxf(t[j].z, t[j].w)));
    }
    const float tmax = waveMax(tm);

    // Per-element factors: E = 2^(t-tmax), F = 2^(0.2(t-tmax)).
    f32x4 E[8], F[8];
    #pragma unroll
    for (int j = 0; j < 8; ++j) {
        f32x4 d;
        d.x = t[j].x - tmax; d.y = t[j].y - tmax;
        d.z = t[j].z - tmax; d.w = t[j].w - tmax;
        E[j].x = __builtin_exp2f(d.x); E[j].y = __builtin_exp2f(d.y);
        E[j].z = __builtin_exp2f(d.z); E[j].w = __builtin_exp2f(d.w);
        F[j].x = __builtin_exp2f(0.2f * d.x); F[j].y = __builtin_exp2f(0.2f * d.y);
        F[j].z = __builtin_exp2f(0.2f * d.z); F[j].w = __builtin_exp2f(0.2f * d.w);
    }

    #pragma unroll
    for (int r = 0; r < ROWS_PER_WAVE; ++r) {
        const int row = row0 + r;
        const float s = S[row];
        const float u = s + tmax;
        const float M = lk(u);                      // exact rowmax (leaky monotone)
        const float A  = __builtin_exp2f(u - M);          // pos-branch row factor
        const float Bc = __builtin_exp2f(0.2f * u - M);   // neg-branch row factor

        // e = max(A*E, Bc*F) == 2^(leaky(s+t)-M) exactly
        f32x4 e[8];
        float ls = 0.f;
        #pragma unroll
        for (int j = 0; j < 8; ++j) {
            e[j].x = fmaxf(A * E[j].x, Bc * F[j].x);
            e[j].y = fmaxf(A * E[j].y, Bc * F[j].y);
            e[j].z = fmaxf(A * E[j].z, Bc * F[j].z);
            e[j].w = fmaxf(A * E[j].w, Bc * F[j].w);
            ls += (e[j].x + e[j].y) + (e[j].z + e[j].w);
        }
        ls = waveSum(ls);
        const float inv = 1.f / ls;

        f32x4* o4 = (f32x4*)(out + (size_t)row * NN);
        #pragma unroll
        for (int j = 0; j < 8; ++j) {
            f32x4 o;
            o.x = e[j].x * inv; o.y = e[j].y * inv;
            o.z = e[j].z * inv; o.w = e[j].w * inv;
            o4[lane + 64 * j] = o;   // regular store (A/B vs nontemporal)
        }
    }
}

extern "C" void kernel_launch(void* const* d_in, const int* in_sizes, int n_in,
                              void* d_out, int out_size, void* d_ws, size_t ws_size,
                              hipStream_t stream) {
    const float* enc  = (const float*)d_in[0];  // [B,N,F]
    const float* kmat = (const float*)d_in[1];  // [F,1,F]
    const float* aks  = (const float*)d_in[2];  // [F,1,1]
    const float* akn  = (const float*)d_in[3];  // [F,1,1]
    float* out = (float*)d_out;                 // [B,N,N]

    float* W = (float*)d_ws;
    float* S = W;                 // B*N = 16384
    float* T = W + BB * NN;       // 16384

    scores_fused<<<BB * NN / 256, 256, 0, stream>>>(enc, kmat, aks, akn, S, T);
    softmax_kernel<<<BB * NN / (4 * ROWS_PER_WAVE), 256, 0, stream>>>(S, T, out);
}